// Round 7
// baseline (445.440 us; speedup 1.0000x reference)
//
#include <hip/hip_runtime.h>
#include <math.h>

#define INV_EPS  (-20.0f)                 // -1/0.05
#define QINV     (1.0f / 65535.0f)
#define LN65535  11.090354888959125f
#define TOLV     0.001f
#define MAX_ITER 50
#define NBLK     256
#define NTHR     1024

// ---- workspace layout ----
#define CTRL_CNT(g)   ((g) * 64)
#define CTRL_GEN(g)   ((g) * 64 + 32)
#define CTRL_ARR(d)   (2048 + (d) * 32)
#define CTRL_CHG(d)   (3648 + (d) * 32)
#define CTRL_INTS     5248
#define Q_OFF_BYTES   (1u << 20)           // compact u16 E rows 4-7 at ws+1MB (32 MB)

#define RX __ATOMIC_RELAXED
#define SC __HIP_MEMORY_SCOPE_AGENT

__device__ __forceinline__ float wave_red_sum64(float x) {
    x += __int_as_float(__builtin_amdgcn_update_dpp(0, __float_as_int(x), 0x111, 0xf, 0xf, false));
    x += __int_as_float(__builtin_amdgcn_update_dpp(0, __float_as_int(x), 0x112, 0xf, 0xf, false));
    x += __int_as_float(__builtin_amdgcn_update_dpp(0, __float_as_int(x), 0x114, 0xf, 0xf, false));
    x += __int_as_float(__builtin_amdgcn_update_dpp(0, __float_as_int(x), 0x118, 0xf, 0xf, false));
    x += __int_as_float(__builtin_amdgcn_update_dpp(0, __float_as_int(x), 0x142, 0xf, 0xf, false));
    x += __int_as_float(__builtin_amdgcn_update_dpp(0, __float_as_int(x), 0x143, 0xf, 0xf, false));
    return __int_as_float(__builtin_amdgcn_readlane(__float_as_int(x), 63));
}

// 8-block (one batch) barrier, relaxed atomics only (no acq/rel => no L2
// writeback/invalidate => XCD L2 + IC stay warm; proven R2-R6).
__device__ __forceinline__ void group_sync(int* cnt, int* gen) {
    __syncthreads();
    if (threadIdx.x == 0) {
        int g = __hip_atomic_load(gen, RX, SC);
        int a = __hip_atomic_fetch_add(cnt, 1, RX, SC);
        if (a == 7) {
            __hip_atomic_store(cnt, 0, RX, SC);
            __hip_atomic_store(gen, g + 1, RX, SC);
        } else {
            while (__hip_atomic_load(gen, RX, SC) == g)
                __builtin_amdgcn_s_sleep(1);
        }
    }
    __syncthreads();
}

// Linear-E row math (R6-proven): row sum s = sum q*evs, u update, col accum.
#define ROWMATH(LR)                                                            \
  {                                                                            \
    float sA = fmaf(qf0, evs0, fmaf(qf4, evs4, fmaf(qf8,  evs8,  qf12*evs12)));\
    float sB = fmaf(qf1, evs1, fmaf(qf5, evs5, fmaf(qf9,  evs9,  qf13*evs13)));\
    float sC = fmaf(qf2, evs2, fmaf(qf6, evs6, fmaf(qf10, evs10, qf14*evs14)));\
    float sD = fmaf(qf3, evs3, fmaf(qf7, evs7, fmaf(qf11, evs11, qf15*evs15)));\
    float s = (sA + sB) + (sC + sD);                                           \
    s = wave_red_sum64(s);                                                     \
    float u_new = lg_src[LR] - __logf(s);                                      \
    flag |= (fabsf(u_new - u_ring[pv][LR]) >= TOLV);                           \
    if (lane == 0) u_ring[cur][LR] = u_new;                                    \
    float eu = __expf(u_new);                                                  \
    cs0 = fmaf(qf0, eu, cs0);   cs1 = fmaf(qf1, eu, cs1);                      \
    cs2 = fmaf(qf2, eu, cs2);   cs3 = fmaf(qf3, eu, cs3);                      \
    cs4 = fmaf(qf4, eu, cs4);   cs5 = fmaf(qf5, eu, cs5);                      \
    cs6 = fmaf(qf6, eu, cs6);   cs7 = fmaf(qf7, eu, cs7);                      \
    cs8 = fmaf(qf8, eu, cs8);   cs9 = fmaf(qf9, eu, cs9);                      \
    cs10 = fmaf(qf10, eu, cs10); cs11 = fmaf(qf11, eu, cs11);                  \
    cs12 = fmaf(qf12, eu, cs12); cs13 = fmaf(qf13, eu, cs13);                  \
    cs14 = fmaf(qf14, eu, cs14); cs15 = fmaf(qf15, eu, cs15);                  \
  }

#define ROW_LIN(QA, QB, LR)                                                    \
  {                                                                            \
    float qf0  = (float)((QA).x & 0xffffu), qf1  = (float)((QA).x >> 16),      \
          qf2  = (float)((QA).y & 0xffffu), qf3  = (float)((QA).y >> 16),      \
          qf4  = (float)((QA).z & 0xffffu), qf5  = (float)((QA).z >> 16),      \
          qf6  = (float)((QA).w & 0xffffu), qf7  = (float)((QA).w >> 16),      \
          qf8  = (float)((QB).x & 0xffffu), qf9  = (float)((QB).x >> 16),      \
          qf10 = (float)((QB).y & 0xffffu), qf11 = (float)((QB).y >> 16),      \
          qf12 = (float)((QB).z & 0xffffu), qf13 = (float)((QB).z >> 16),      \
          qf14 = (float)((QB).w & 0xffffu), qf15 = (float)((QB).w >> 16);      \
    ROWMATH(LR)                                                                \
  }

// colAcc index: cc(col) = col + (col>>4); for col = c*256 + lane*4 + jj this
// is (c*272 + (lane<<2)+(lane>>2) + jj). Padding makes the 16 ds_add_f32 per
// lane <=2-way bank-aliased (free, m136). Single pass replaces the 69.6 KB
// smS stage+combine -> frees LDS for the q stash.
#define COL_ATOMIC                                                             \
  { const int lb = (lane << 2) + (lane >> 2);                                  \
    atomicAdd(&colAcc[lb      ], cs0);  atomicAdd(&colAcc[lb +   1], cs1);     \
    atomicAdd(&colAcc[lb +   2], cs2);  atomicAdd(&colAcc[lb +   3], cs3);     \
    atomicAdd(&colAcc[lb + 272], cs4);  atomicAdd(&colAcc[lb + 273], cs5);     \
    atomicAdd(&colAcc[lb + 274], cs6);  atomicAdd(&colAcc[lb + 275], cs7);     \
    atomicAdd(&colAcc[lb + 544], cs8);  atomicAdd(&colAcc[lb + 545], cs9);     \
    atomicAdd(&colAcc[lb + 546], cs10); atomicAdd(&colAcc[lb + 547], cs11);    \
    atomicAdd(&colAcc[lb + 816], cs12); atomicAdd(&colAcc[lb + 817], cs13);    \
    atomicAdd(&colAcc[lb + 818], cs14); atomicAdd(&colAcc[lb + 819], cs15); }

// LDS q stash index: wave widx, row r (0-3), half p (0-1)
#define LQS(r, p) (((((widx << 2) | (r)) << 1) | (p)) * 64 + lane)

// epilogue row: out = q * (eu * ev/65535); evS staged in lg_tgt
#define EPI_ROW(QA, QB, i)                                                     \
  { const float uu = __expf(u_ring[slot][(widx << 3) + (i)]);                  \
    float* op = out + (((size_t)(rowb + (widx << 3) + (i))) << 10) + (lane << 2); \
    float4 ev, o;                                                              \
    ev = *(const float4*)&lg_tgt[lane << 2];                                   \
    o.x = (float)((QA).x & 0xffffu) * (uu * ev.x);                             \
    o.y = (float)((QA).x >> 16)     * (uu * ev.y);                             \
    o.z = (float)((QA).y & 0xffffu) * (uu * ev.z);                             \
    o.w = (float)((QA).y >> 16)     * (uu * ev.w);                             \
    *(float4*)(op) = o;                                                        \
    ev = *(const float4*)&lg_tgt[256 + (lane << 2)];                           \
    o.x = (float)((QA).z & 0xffffu) * (uu * ev.x);                             \
    o.y = (float)((QA).z >> 16)     * (uu * ev.y);                             \
    o.z = (float)((QA).w & 0xffffu) * (uu * ev.z);                             \
    o.w = (float)((QA).w >> 16)     * (uu * ev.w);                             \
    *(float4*)(op + 256) = o;                                                  \
    ev = *(const float4*)&lg_tgt[512 + (lane << 2)];                           \
    o.x = (float)((QB).x & 0xffffu) * (uu * ev.x);                             \
    o.y = (float)((QB).x >> 16)     * (uu * ev.y);                             \
    o.z = (float)((QB).y & 0xffffu) * (uu * ev.z);                             \
    o.w = (float)((QB).y >> 16)     * (uu * ev.w);                             \
    *(float4*)(op + 512) = o;                                                  \
    ev = *(const float4*)&lg_tgt[768 + (lane << 2)];                           \
    o.x = (float)((QB).z & 0xffffu) * (uu * ev.x);                             \
    o.y = (float)((QB).z >> 16)     * (uu * ev.y);                             \
    o.z = (float)((QB).w & 0xffffu) * (uu * ev.z);                             \
    o.w = (float)((QB).w >> 16)     * (uu * ev.w);                             \
    *(float4*)(op + 768) = o; }

// QM=1: E = exp(-20C) u16 linear. Rows 0-3 of each wave's 8-row group live in
//       a 128 KB LDS stash (it0 fills it); rows 4-7 stream from a compact
//       32 MB qbuf (4 MB/XCD ~ L2-sized). No loop-carried q registers (R4's
//       spill trap). No per-element exp in steady loop or epilogue.
// QM=0: fp32-streaming fallback (ws too small).
template<int QM>
__global__ __launch_bounds__(NTHR, 4) void sinkhorn_fused(
    const float* __restrict__ cost, const float* __restrict__ src,
    const float* __restrict__ tgt, float* __restrict__ out,
    int* __restrict__ ctrl, uint* __restrict__ qbuf)
{
    const int t    = threadIdx.x;
    const int lane = t & 63;
    const int widx = t >> 6;
    const int rx   = blockIdx.x & 7;
    const int sx   = blockIdx.x >> 3;
    const int grp  = rx * 4 + (sx >> 3);    // batch id, 0..31
    const int j    = sx & 7;                // 128-row slab within batch

    __shared__ float colAcc[1088];
    __shared__ float v_ring[4][1024];
    __shared__ float u_ring[4][128];
    __shared__ float lg_tgt[1024];
    __shared__ float lg_src[128];
    __shared__ uint4 qstash[QM == 1 ? 8192 : 1];   // 128 KB: rows 0-3 per wave
    __shared__ int   s_chg, s_stop;

    int* cnt = ctrl + CTRL_CNT(grp);
    int* gen = ctrl + CTRL_GEN(grp);

    const int rowb = (grp << 10) + (j << 7);
    const float* cbase = cost + ((size_t)(rowb + (widx << 3)) << 10) + (lane << 2);
    // compact stream buffer: row-group (rowb>>3)+widx, rows 4-7 only
    uint4* qs4 = nullptr;
    if constexpr (QM == 1)
        qs4 = (uint4*)qbuf + ((size_t)((rowb >> 3) + widx)) * 512 + lane;
    float* const Pg = out + ((size_t)grp << 20);   // group scratch in own out-slab

    lg_tgt[t] = __logf(tgt[(grp << 10) + t] + 1e-12f) + ((QM == 1) ? LN65535 : 0.f);
    if (t < 128) {
        lg_src[t]    = __logf(src[rowb + t] + 1e-12f);
        u_ring[3][t] = 0.f;
    }
    v_ring[3][t] = 0.f;

    // QM=0 persistent fp32 prefetch (rows 0,1 live across iterations)
    float4 f0, f1, f2, f3, g0, g1, g2, g3;
    if constexpr (QM == 0) {
        f0 = *(const float4*)(cbase);
        f1 = *(const float4*)(cbase + 256);
        f2 = *(const float4*)(cbase + 512);
        f3 = *(const float4*)(cbase + 768);
        const float* r1p = cbase + ((size_t)1 << 10);
        g0 = *(const float4*)(r1p);
        g1 = *(const float4*)(r1p + 256);
        g2 = *(const float4*)(r1p + 512);
        g3 = *(const float4*)(r1p + 768);
    }

    __syncthreads();

    int K = -1;
    for (int it = 0; it < MAX_ITER; ++it) {
        const int cur = it & 3, pv = (it + 3) & 3;

        // zero colAcc (consumed after the post-adds barrier last iteration;
        // next touch is atomic adds after THIS barrier -> no race)
        colAcc[t] = 0.f;
        if (t < 64) colAcc[1024 + t] = 0.f;

        // gate on global decision for it-2 (slack-2 pipeline; proven R1-R6)
        if (t == 0) {
            int stop = 0;
            if (it >= 2) {
                const int d = it - 2;
                while (__hip_atomic_load(ctrl + CTRL_ARR(d), RX, SC) != NBLK)
                    __builtin_amdgcn_s_sleep(1);
                stop = (__hip_atomic_load(ctrl + CTRL_CHG(d), RX, SC) == 0);
            }
            s_stop = stop;
            s_chg  = 0;
        }
        __syncthreads();
        if (s_stop) { K = it - 2; break; }   // ring slot (it-2)&3 still live

        bool flag = false;

        if constexpr (QM == 1) {
            const int r8 = widx << 3;
            // evs[k] = exp(v_old[col_k]) / 65535
            const float* vp = &v_ring[pv][lane << 2];
            float4 va = *(const float4*)vp;
            float4 vb = *(const float4*)(vp + 256);
            float4 vc = *(const float4*)(vp + 512);
            float4 vd = *(const float4*)(vp + 768);
            const float evs0  = __expf(va.x)*QINV, evs1  = __expf(va.y)*QINV,
                        evs2  = __expf(va.z)*QINV, evs3  = __expf(va.w)*QINV,
                        evs4  = __expf(vb.x)*QINV, evs5  = __expf(vb.y)*QINV,
                        evs6  = __expf(vb.z)*QINV, evs7  = __expf(vb.w)*QINV,
                        evs8  = __expf(vc.x)*QINV, evs9  = __expf(vc.y)*QINV,
                        evs10 = __expf(vc.z)*QINV, evs11 = __expf(vc.w)*QINV,
                        evs12 = __expf(vd.x)*QINV, evs13 = __expf(vd.y)*QINV,
                        evs14 = __expf(vd.z)*QINV, evs15 = __expf(vd.w)*QINV;
            float cs0=0,cs1=0,cs2=0,cs3=0,cs4=0,cs5=0,cs6=0,cs7=0,
                  cs8=0,cs9=0,cs10=0,cs11=0,cs12=0,cs13=0,cs14=0,cs15=0;

            if (it == 0) {
                // fp32 cost -> E -> quantize -> stash/store -> compute
                float4 a0 = *(const float4*)(cbase);
                float4 a1 = *(const float4*)(cbase + 256);
                float4 a2 = *(const float4*)(cbase + 512);
                float4 a3 = *(const float4*)(cbase + 768);
                const float* r1p = cbase + ((size_t)1 << 10);
                float4 b0 = *(const float4*)(r1p);
                float4 b1 = *(const float4*)(r1p + 256);
                float4 b2 = *(const float4*)(r1p + 512);
                float4 b3 = *(const float4*)(r1p + 768);
                #pragma unroll 1
                for (int i = 0; i < 8; ++i) {
                    const float* nxt = cbase + ((size_t)((i + 2) & 7) << 10);
                    float4 p0 = *(const float4*)(nxt);
                    float4 p1 = *(const float4*)(nxt + 256);
                    float4 p2 = *(const float4*)(nxt + 512);
                    float4 p3 = *(const float4*)(nxt + 768);

                    float qf0  = rintf(__expf(a0.x*INV_EPS)*65535.f);
                    float qf1  = rintf(__expf(a0.y*INV_EPS)*65535.f);
                    float qf2  = rintf(__expf(a0.z*INV_EPS)*65535.f);
                    float qf3  = rintf(__expf(a0.w*INV_EPS)*65535.f);
                    float qf4  = rintf(__expf(a1.x*INV_EPS)*65535.f);
                    float qf5  = rintf(__expf(a1.y*INV_EPS)*65535.f);
                    float qf6  = rintf(__expf(a1.z*INV_EPS)*65535.f);
                    float qf7  = rintf(__expf(a1.w*INV_EPS)*65535.f);
                    float qf8  = rintf(__expf(a2.x*INV_EPS)*65535.f);
                    float qf9  = rintf(__expf(a2.y*INV_EPS)*65535.f);
                    float qf10 = rintf(__expf(a2.z*INV_EPS)*65535.f);
                    float qf11 = rintf(__expf(a2.w*INV_EPS)*65535.f);
                    float qf12 = rintf(__expf(a3.x*INV_EPS)*65535.f);
                    float qf13 = rintf(__expf(a3.y*INV_EPS)*65535.f);
                    float qf14 = rintf(__expf(a3.z*INV_EPS)*65535.f);
                    float qf15 = rintf(__expf(a3.w*INV_EPS)*65535.f);
                    uint4 w0, w1;
                    w0.x = (uint)qf0  | ((uint)qf1  << 16);
                    w0.y = (uint)qf2  | ((uint)qf3  << 16);
                    w0.z = (uint)qf4  | ((uint)qf5  << 16);
                    w0.w = (uint)qf6  | ((uint)qf7  << 16);
                    w1.x = (uint)qf8  | ((uint)qf9  << 16);
                    w1.y = (uint)qf10 | ((uint)qf11 << 16);
                    w1.z = (uint)qf12 | ((uint)qf13 << 16);
                    w1.w = (uint)qf14 | ((uint)qf15 << 16);
                    if (i < 4) {
                        qstash[LQS(i, 0)] = w0;
                        qstash[LQS(i, 1)] = w1;
                    } else {
                        qs4[((i - 4) << 7)]      = w0;
                        qs4[((i - 4) << 7) + 64] = w1;
                    }

                    ROWMATH(r8 + i)

                    a0 = b0; a1 = b1; a2 = b2; a3 = b3;
                    b0 = p0; b1 = p1; b2 = p2; b3 = p3;
                }
            } else {
                // issue stream loads for rows 4-7, hide under LDS rows 0-3
                uint4 p40 = qs4[0],   p41 = qs4[64];
                uint4 p50 = qs4[128], p51 = qs4[192];
                uint4 p60 = qs4[256], p61 = qs4[320];
                uint4 p70 = qs4[384], p71 = qs4[448];
                { uint4 l0 = qstash[LQS(0,0)], l1 = qstash[LQS(0,1)]; ROW_LIN(l0, l1, r8+0) }
                { uint4 l0 = qstash[LQS(1,0)], l1 = qstash[LQS(1,1)]; ROW_LIN(l0, l1, r8+1) }
                { uint4 l0 = qstash[LQS(2,0)], l1 = qstash[LQS(2,1)]; ROW_LIN(l0, l1, r8+2) }
                { uint4 l0 = qstash[LQS(3,0)], l1 = qstash[LQS(3,1)]; ROW_LIN(l0, l1, r8+3) }
                ROW_LIN(p40, p41, r8+4)
                ROW_LIN(p50, p51, r8+5)
                ROW_LIN(p60, p61, r8+6)
                ROW_LIN(p70, p71, r8+7)
            }

            COL_ATOMIC
        } else {
            const float* vp = &v_ring[pv][lane << 2];
            float4 vo0 = *(const float4*)(vp);
            float4 vo1 = *(const float4*)(vp + 256);
            float4 vo2 = *(const float4*)(vp + 512);
            float4 vo3 = *(const float4*)(vp + 768);
            float cs[16];
            #pragma unroll
            for (int s = 0; s < 16; ++s) cs[s] = 0.f;
            #pragma unroll 1
            for (int i = 0; i < 8; ++i) {
                const float* nxt = cbase + ((size_t)((i + 2) & 7) << 10);
                float4 p0 = *(const float4*)(nxt);
                float4 p1 = *(const float4*)(nxt + 256);
                float4 p2 = *(const float4*)(nxt + 512);
                float4 p3 = *(const float4*)(nxt + 768);
                float e[16];
                e[ 0] = __expf(fmaf(f0.x, INV_EPS, vo0.x));
                e[ 1] = __expf(fmaf(f0.y, INV_EPS, vo0.y));
                e[ 2] = __expf(fmaf(f0.z, INV_EPS, vo0.z));
                e[ 3] = __expf(fmaf(f0.w, INV_EPS, vo0.w));
                e[ 4] = __expf(fmaf(f1.x, INV_EPS, vo1.x));
                e[ 5] = __expf(fmaf(f1.y, INV_EPS, vo1.y));
                e[ 6] = __expf(fmaf(f1.z, INV_EPS, vo1.z));
                e[ 7] = __expf(fmaf(f1.w, INV_EPS, vo1.w));
                e[ 8] = __expf(fmaf(f2.x, INV_EPS, vo2.x));
                e[ 9] = __expf(fmaf(f2.y, INV_EPS, vo2.y));
                e[10] = __expf(fmaf(f2.z, INV_EPS, vo2.z));
                e[11] = __expf(fmaf(f2.w, INV_EPS, vo2.w));
                e[12] = __expf(fmaf(f3.x, INV_EPS, vo3.x));
                e[13] = __expf(fmaf(f3.y, INV_EPS, vo3.y));
                e[14] = __expf(fmaf(f3.z, INV_EPS, vo3.z));
                e[15] = __expf(fmaf(f3.w, INV_EPS, vo3.w));
                float s01 = e[0]+e[1],   s23 = e[2]+e[3];
                float s45 = e[4]+e[5],   s67 = e[6]+e[7];
                float s89 = e[8]+e[9],   sab = e[10]+e[11];
                float scd = e[12]+e[13], sef = e[14]+e[15];
                float s = ((s01+s23)+(s45+s67)) + ((s89+sab)+(scd+sef));
                s = wave_red_sum64(s);
                const int lr = (widx << 3) + i;
                float u_new = lg_src[lr] - __logf(s);
                flag |= (fabsf(u_new - u_ring[pv][lr]) >= TOLV);
                if (lane == 0) u_ring[cur][lr] = u_new;
                float eu = __expf(u_new);
                #pragma unroll
                for (int k = 0; k < 16; ++k)
                    cs[k] = fmaf(e[k], eu, cs[k]);
                f0 = g0; f1 = g1; f2 = g2; f3 = g3;
                g0 = p0; g1 = p1; g2 = p2; g3 = p3;
            }
            const int lb = (lane << 2) + (lane >> 2);
            #pragma unroll
            for (int k = 0; k < 16; ++k)
                atomicAdd(&colAcc[(k >> 2) * 272 + lb + (k & 3)], cs[k]);
        }

        if (lane == 0 && flag) s_chg = 1;
        __syncthreads();   // adds done; also drains vmcnt (it0 q-stores visible)

        // publish: chg-or IC-complete before arrival add
        if (t == 0) {
            if (s_chg)
                __hip_atomic_fetch_or(ctrl + CTRL_CHG(it), 1, RX, SC);
            asm volatile("s_waitcnt vmcnt(0)" ::: "memory");
            __hip_atomic_fetch_add(ctrl + CTRL_ARR(it), 1, RX, SC);
        }

        // block partial for column t
        float* Pb = Pg + (size_t)(((it & 1) << 3) + j) * 1040;
        {
            float S = colAcc[t + (t >> 4)];
            if constexpr (QM == 0) S *= __expf(-v_ring[pv][t]);
            __hip_atomic_store(Pb + t, S, RX, SC);
        }

        group_sync(cnt, gen);   // all 8 slabs' partials IC-visible

        // redundant v-combine (bitwise-identical across the 8 blocks)
        {
            float* Pf = Pg + (size_t)((it & 1) << 3) * 1040;
            float S = 0.f;
            #pragma unroll
            for (int jj = 0; jj < 8; ++jj)
                S += __hip_atomic_load(Pf + jj * 1040 + t, RX, SC);
            v_ring[cur][t] = lg_tgt[t] - __logf(S);
        }
        __syncthreads();
    }

    if (K < 0) {   // ran to 50: only d=48 undecided
        if (t == 0) {
            while (__hip_atomic_load(ctrl + CTRL_ARR(48), RX, SC) != NBLK)
                __builtin_amdgcn_s_sleep(1);
            s_stop = (__hip_atomic_load(ctrl + CTRL_CHG(48), RX, SC) == 0);
        }
        __syncthreads();
        K = s_stop ? 48 : 49;
    }

    group_sync(cnt, gen);   // siblings done reading partials

    {
        const int slot = K & 3;
        if constexpr (QM == 1) {
            // issue stream loads early; evS staged in lg_tgt (last used in the
            // final v-combine, all threads of this block past it)
            uint4 p40 = qs4[0],   p41 = qs4[64];
            uint4 p50 = qs4[128], p51 = qs4[192];
            uint4 p60 = qs4[256], p61 = qs4[320];
            uint4 p70 = qs4[384], p71 = qs4[448];
            lg_tgt[t] = __expf(v_ring[slot][t]) * QINV;
            __syncthreads();
            { uint4 l0 = qstash[LQS(0,0)], l1 = qstash[LQS(0,1)]; EPI_ROW(l0, l1, 0) }
            { uint4 l0 = qstash[LQS(1,0)], l1 = qstash[LQS(1,1)]; EPI_ROW(l0, l1, 1) }
            { uint4 l0 = qstash[LQS(2,0)], l1 = qstash[LQS(2,1)]; EPI_ROW(l0, l1, 2) }
            { uint4 l0 = qstash[LQS(3,0)], l1 = qstash[LQS(3,1)]; EPI_ROW(l0, l1, 3) }
            EPI_ROW(p40, p41, 4)
            EPI_ROW(p50, p51, 5)
            EPI_ROW(p60, p61, 6)
            EPI_ROW(p70, p71, 7)
        } else {
            const size_t base = ((size_t)rowb) << 10;
            #pragma unroll 1
            for (int i = 0; i < 32; ++i) {
                const int g4  = (i << 10) + t;
                const int lr  = g4 >> 8;
                const int c4  = (g4 & 255) << 2;
                const size_t e = base + ((size_t)g4 << 2);
                float4 cc = *(const float4*)(cost + e);
                float4 vv = *(const float4*)&v_ring[slot][c4];
                const float uu = u_ring[slot][lr];
                float4 o;
                o.x = __expf(fmaf(cc.x, INV_EPS, uu + vv.x));
                o.y = __expf(fmaf(cc.y, INV_EPS, uu + vv.y));
                o.z = __expf(fmaf(cc.z, INV_EPS, uu + vv.z));
                o.w = __expf(fmaf(cc.w, INV_EPS, uu + vv.w));
                *(float4*)(out + e) = o;
            }
        }
    }
}

extern "C" void kernel_launch(void* const* d_in, const int* in_sizes, int n_in,
                              void* d_out, int out_size, void* d_ws, size_t ws_size,
                              hipStream_t stream) {
    const float* cost = (const float*)d_in[0];
    const float* src  = (const float*)d_in[1];
    const float* tgt  = (const float*)d_in[2];
    float* out = (float*)d_out;
    int*   ctrl = (int*)d_ws;
    (void)in_sizes; (void)n_in; (void)out_size;

    hipMemsetAsync(d_ws, 0, CTRL_INTS * sizeof(int), stream);

    const size_t need = (size_t)Q_OFF_BYTES + ((size_t)32 << 20);
    if (ws_size >= need) {
        uint* qbuf = (uint*)((char*)d_ws + Q_OFF_BYTES);
        sinkhorn_fused<1><<<dim3(NBLK), dim3(NTHR), 0, stream>>>(
            cost, src, tgt, out, ctrl, qbuf);
    } else {
        sinkhorn_fused<0><<<dim3(NBLK), dim3(NTHR), 0, stream>>>(
            cost, src, tgt, out, ctrl, nullptr);
    }
}